// Round 8
// baseline (381.989 us; speedup 1.0000x reference)
//
#include <hip/hip_runtime.h>
#include <math.h>

#define W 512
#define H 512
#define S (W * H)        // 262144
#define B 8
#define NIMG 16
#define CORE 64
#define HALO 12
#define LDT 88           // tile cols
#define LROWS 90         // LDS rows 0..89; data rows 1..88 = image rows y0..y0+87
#define NQ 22            // quads per row
#define FINF __builtin_huge_valf()

__device__ __forceinline__ float4 ld4s(const float* p) { return *(const float4*)p; }
__device__ __forceinline__ void st4s(float* p, float4 v) { *(float4*)p = v; }

__device__ __forceinline__ float blockReduce(float v, float* sw) {
    #pragma unroll
    for (int o = 32; o; o >>= 1) v += __shfl_down(v, o, 64);
    int lane = threadIdx.x & 63, wid = threadIdx.x >> 6;
    if (lane == 0) sw[wid] = v;
    __syncthreads();
    float r = (threadIdx.x < 4) ? sw[threadIdx.x] : 0.f;
    if (wid == 0) { r += __shfl_down(r, 2, 64); r += __shfl_down(r, 1, 64); }
    __syncthreads();
    return r;
}

// ---------------------------------------------------------------- phase 1
__global__ __launch_bounds__(256) void phase1_kernel(
        const float* __restrict__ net, const int* __restrict__ yt,
        float* __restrict__ J0, double* __restrict__ pb,
        double* __restrict__ acc) {
    __shared__ float sw[4];
    const int tid = threadIdx.x;
    if (blockIdx.x == 0 && tid < 48) acc[tid] = 0.0;
    float inter = 0.f, sp = 0.f, sy = 0.f;
    for (int i = blockIdx.x * 256 + tid; i < B * S / 4; i += 1024 * 256) {
        int b = i >> 16;
        int s = (i & 65535) << 2;
        const float* nb = net + (size_t)b * 2 * S;
        float4 x0 = ld4s(nb + s);
        float4 x1 = ld4s(nb + S + s);
        int4 yv = *(const int4*)(yt + (size_t)b * S + s);
        float4 p, yf;
        p.x = 1.f / (1.f + expf(x0.x - x1.x));
        p.y = 1.f / (1.f + expf(x0.y - x1.y));
        p.z = 1.f / (1.f + expf(x0.z - x1.z));
        p.w = 1.f / (1.f + expf(x0.w - x1.w));
        yf.x = (float)yv.x; yf.y = (float)yv.y; yf.z = (float)yv.z; yf.w = (float)yv.w;
        st4s(J0 + (size_t)b * S + s, p);
        st4s(J0 + (size_t)(B + b) * S + s, yf);
        inter += p.x * yf.x + p.y * yf.y + p.z * yf.z + p.w * yf.w;
        sp += p.x + p.y + p.z + p.w;
        sy += yf.x + yf.y + yf.z + yf.w;
    }
    float v;
    v = blockReduce(inter, sw); if (tid == 0) pb[blockIdx.x * 3 + 0] = (double)v;
    v = blockReduce(sp, sw);    if (tid == 0) pb[blockIdx.x * 3 + 1] = (double)v;
    v = blockReduce(sy, sw);    if (tid == 0) pb[blockIdx.x * 3 + 2] = (double)v;
}

// ---------------------------------------------------------------- fused skeleton
// Merged-phase double-buffered: per phase, ONE 6-row window read serves BOTH
// the previous round's dilate (vertical-max-first, Jc carry for delta) AND the
// current round's erode (written immediately to the other buffer). 1 barrier
// per phase (write buf != read buf; WAR separated by the phase barrier).
// Erode grid fixed+aligned: 22 slabs x 22 quads = 484 units <= 512 threads ->
// single balanced sweep; core = slabs/quads 3..18. Creep from unwritten LDS
// rows 0/89, cols 0..3/84..87 advances <=1/phase, reaching <=6 < 11 = min
// row/col any dilate window touches -> safe.
template <bool INIT>
__global__ __launch_bounds__(512, 4) void skel_fused_kernel(
        const float* __restrict__ Jin, float* __restrict__ Jout,
        float* __restrict__ skel, int NR) {
    __shared__ float Jl[2][LROWS * LDT];   // 2 x 90 x 88 floats = 63360 B
    const int tid = threadIdx.x;
    const int lane = tid & 63;
    const int img = blockIdx.x >> 6;
    const int t64 = blockIdx.x & 63;
    const int ty = t64 >> 3, tx = t64 & 7;
    const int yb = ty * CORE - 13;      // image row of LDS row 0
    const int x0 = tx * CORE - HALO;    // image col of LDS col 0
    const float* Ji = Jin + (size_t)img * S;
    float* Jo = Jout + (size_t)img * S;
    float* Sk = skel + (size_t)img * S;
    const bool interior = (ty > 0) & (ty < 7) & (tx > 0) & (tx < 7);

    // ---- load 90x88 into buf 0 (interior blocks: rows 0..89 all in-image)
    if (interior) {
        for (int i = tid; i < LROWS * NQ; i += 512) {
            int r = i / NQ, q = i - (i / NQ) * NQ;
            st4s(&Jl[0][r * LDT + (q << 2)],
                 ld4s(Ji + (yb + r) * W + x0 + (q << 2)));
        }
    } else {
        for (int i = tid; i < LROWS * NQ; i += 512) {
            int r = i / NQ, q = i - (i / NQ) * NQ;
            int gy = yb + r, gx = x0 + (q << 2);
            float4 v;
            if ((unsigned)gy < H && (unsigned)gx < W) v = ld4s(Ji + gy * W + gx);
            else v = make_float4(FINF, FINF, FINF, FINF);
            st4s(&Jl[0][r * LDT + (q << 2)], v);
        }
    }

    const int ei = tid / 22;            // slab 0..21 (for tid<484)
    const int eq = tid - ei * 22;       // quad 0..21
    const int erow = ei << 2;           // window rows erow..erow+5, outputs erow+1..erow+4
    const int ecol = eq << 2;
    const int gxc = x0 + ecol;
    const bool eact = (tid < 484);
    const bool dilA = eact && (ei >= 3) && (ei <= 18) && (eq >= 3) && (eq <= 18);
    const bool cOOB = (!interior) && ((unsigned)gxc >= W);

    float4 sk4[4], Jc[4];
    if (dilA) {
        #pragma unroll
        for (int j = 0; j < 4; ++j) {
            if (INIT) sk4[j] = make_float4(0.f, 0.f, 0.f, 0.f);
            else      sk4[j] = ld4s(Sk + (yb + erow + 1 + j) * W + gxc);
        }
    }
    __syncthreads();

    int cur = 0;
    for (int p = 0; ; ++p) {
        const bool doE = (p < NR);
        const bool doD = (p > 0);
        const float* A = Jl[cur];
        float* Bb = Jl[cur ^ 1];
        if (eact) {
            const float* bp = A + erow * LDT + ecol;
            float4 Wm = ld4s(bp);            // row erow
            float4 Wc = ld4s(bp + LDT);      // row erow+1
            #pragma unroll
            for (int j = 1; j <= 4; ++j) {
                float4 Wp = ld4s(bp + (j + 1) * LDT);
                const int d = erow + j;
                const int gy = yb + d;
                // ---------- erode E_p (cross-min, +inf pad) ----------
                if (doE) {
                    float lw = __shfl_up(Wc.w, 1, 64);
                    float rx = __shfl_down(Wc.x, 1, 64);
                    if (lane == 0 && eq > 0)   lw = A[d * LDT + ecol - 1];
                    if (lane == 63 && eq < 21) rx = A[d * LDT + ecol + 4];
                    if (eq == 0)  lw = FINF;
                    if (eq == 21) rx = FINF;
                    float4 e;
                    e.x = fminf(fminf(fminf(Wm.x, Wp.x), fminf(lw,   Wc.y)), Wc.x);
                    e.y = fminf(fminf(fminf(Wm.y, Wp.y), fminf(Wc.x, Wc.z)), Wc.y);
                    e.z = fminf(fminf(fminf(Wm.z, Wp.z), fminf(Wc.y, Wc.w)), Wc.z);
                    e.w = fminf(fminf(fminf(Wm.w, Wp.w), fminf(Wc.z, rx  )), Wc.w);
                    if (!interior && (((unsigned)gy >= H) | cOOB))
                        e = make_float4(FINF, FINF, FINF, FINF);
                    st4s(&Bb[d * LDT + ecol], e);
                }
                // ---------- dilate D_{p-1} + skel (core threads) ----------
                if (doD) {
                    // vertical max first (computed by ALL eact threads so the
                    // lane shuffles below have valid sources at q=2/19)
                    float4 am = Wm, ap = Wp;
                    if (!interior) {
                        if (gy == 0)     am = make_float4(-FINF, -FINF, -FINF, -FINF);
                        if (gy == H - 1) ap = make_float4(-FINF, -FINF, -FINF, -FINF);
                    }
                    float4 vm;
                    vm.x = fmaxf(fmaxf(am.x, ap.x), Wc.x);
                    vm.y = fmaxf(fmaxf(am.y, ap.y), Wc.y);
                    vm.z = fmaxf(fmaxf(am.z, ap.z), Wc.z);
                    vm.w = fmaxf(fmaxf(am.w, ap.w), Wc.w);
                    float lwv = __shfl_up(vm.w, 1, 64);
                    float rxv = __shfl_down(vm.x, 1, 64);
                    if (dilA) {
                        if (lane == 0) {     // wave-boundary fallback, col ecol-1
                            float v0 = A[(d - 1) * LDT + ecol - 1];
                            float v1 = A[d * LDT + ecol - 1];
                            float v2 = A[(d + 1) * LDT + ecol - 1];
                            if (!interior) {
                                if (gy == 0)     v0 = -FINF;
                                if (gy == H - 1) v2 = -FINF;
                            }
                            lwv = fmaxf(fmaxf(v0, v1), v2);
                        }
                        if (lane == 63) {    // wave-boundary fallback, col ecol+4
                            float v0 = A[(d - 1) * LDT + ecol + 4];
                            float v1 = A[d * LDT + ecol + 4];
                            float v2 = A[(d + 1) * LDT + ecol + 4];
                            if (!interior) {
                                if (gy == 0)     v0 = -FINF;
                                if (gy == H - 1) v2 = -FINF;
                            }
                            rxv = fmaxf(fmaxf(v0, v1), v2);
                        }
                        if (!interior) {
                            if (gxc == 0)     lwv = -FINF;   // image left edge
                            if (gxc == W - 4) rxv = -FINF;   // image right edge
                        }
                        float4 dm;
                        dm.x = fmaxf(fmaxf(lwv,  vm.x), vm.y);
                        dm.y = fmaxf(fmaxf(vm.x, vm.y), vm.z);
                        dm.z = fmaxf(fmaxf(vm.y, vm.z), vm.w);
                        dm.w = fmaxf(fmaxf(vm.z, vm.w), rxv);
                        float4 Jv = Jc[j - 1];    // J_{p-1} core row (carried)
                        float d0 = fmaxf(Jv.x - dm.x, 0.f);
                        float d1 = fmaxf(Jv.y - dm.y, 0.f);
                        float d2 = fmaxf(Jv.z - dm.z, 0.f);
                        float d3 = fmaxf(Jv.w - dm.w, 0.f);
                        sk4[j-1].x += fmaxf(d0 - sk4[j-1].x * d0, 0.f);
                        sk4[j-1].y += fmaxf(d1 - sk4[j-1].y * d1, 0.f);
                        sk4[j-1].z += fmaxf(d2 - sk4[j-1].z * d2, 0.f);
                        sk4[j-1].w += fmaxf(d3 - sk4[j-1].w * d3, 0.f);
                    }
                }
                Jc[j - 1] = Wc;    // J_p core row -> next phase's delta input
                Wm = Wc; Wc = Wp;
            }
        }
        if (p == NR) break;        // final phase: no write, no barrier needed
        __syncthreads();           // the ONLY barrier per phase
        cur ^= 1;
    }

    // epilogue: Jout = E_{NR-1} core (== Jc after last phase), skel out
    if (dilA) {
        #pragma unroll
        for (int j = 0; j < 4; ++j) {
            int gy = yb + erow + 1 + j;
            st4s(Jo + gy * W + gxc, Jc[j]);
            st4s(Sk + gy * W + gxc, sk4[j]);
        }
    }
}

// ---------------------------------------------------------------- endpoints
__global__ __launch_bounds__(256) void endpoint_kernel(
        const float* __restrict__ skel, double* __restrict__ acc) {
    __shared__ float sR[10][520];
    __shared__ float sw[4];
    const int tid = threadIdx.x;
    const int img = blockIdx.x >> 6;
    const int rb = blockIdx.x & 63;
    const int yB = rb << 3;
    const float* Sk = skel + (size_t)img * S;
    for (int i = tid; i < 1280; i += 256) {
        int r = i >> 7, c4 = i & 127;
        int gy = yB - 1 + r;
        float4 v = make_float4(0.f, 0.f, 0.f, 0.f);
        if ((unsigned)gy < H) v = ld4s(Sk + gy * W + (c4 << 2));
        st4s(&sR[r][4 + (c4 << 2)], v);
    }
    if (tid < 10) { sR[tid][3] = 0.f; sR[tid][516] = 0.f; }
    __syncthreads();
    float t = 0.f, syA = 0.f, sxA = 0.f;
    #pragma unroll
    for (int k = 0; k < 4; ++k) {
        int qidx = k * 256 + tid;
        int rrow = qidx >> 7;
        int x = (qidx & 127) << 2;
        int r = 1 + rrow;
        float gy = (float)(yB + rrow);
        const float* Rm = &sR[r - 1][4 + x];
        const float* Rc = &sR[r][4 + x];
        const float* Rp = &sR[r + 1][4 + x];
        float4 bm = ld4s(Rm); float lm = ld4s(Rm - 4).w, rm = ld4s(Rm + 4).x;
        float4 bc = ld4s(Rc); float lc = ld4s(Rc - 4).w, rc = ld4s(Rc + 4).x;
        float4 bp = ld4s(Rp); float lp = ld4s(Rp - 4).w, rp = ld4s(Rp + 4).x;
        float hm0 = lm + bm.x + bm.y, hm1 = bm.x + bm.y + bm.z;
        float hm2 = bm.y + bm.z + bm.w, hm3 = bm.z + bm.w + rm;
        float hc0 = lc + bc.x + bc.y, hc1 = bc.x + bc.y + bc.z;
        float hc2 = bc.y + bc.z + bc.w, hc3 = bc.z + bc.w + rc;
        float hp0 = lp + bp.x + bp.y, hp1 = bp.x + bp.y + bp.z;
        float hp2 = bp.y + bp.z + bp.w, hp3 = bp.z + bp.w + rp;
        float ns0 = hm0 + hc0 + hp0 + 9.f * bc.x;
        float ns1 = hm1 + hc1 + hp1 + 9.f * bc.y;
        float ns2 = hm2 + hc2 + hp2 + 9.f * bc.z;
        float ns3 = hm3 + hc3 + hp3 + 9.f * bc.w;
        float e0 = ns0 - 11.f, e1 = ns1 - 11.f, e2 = ns2 - 11.f, e3 = ns3 - 11.f;
        float ep0 = expf(-e0 * e0) * bc.x;
        float ep1 = expf(-e1 * e1) * bc.y;
        float ep2 = expf(-e2 * e2) * bc.z;
        float ep3 = expf(-e3 * e3) * bc.w;
        float es = ep0 + ep1 + ep2 + ep3;
        t += es;
        syA += gy * es;
        sxA += ep0 * (float)(x + 0) + ep1 * (float)(x + 1)
             + ep2 * (float)(x + 2) + ep3 * (float)(x + 3);
    }
    float v;
    v = blockReduce(t, sw);   if (tid == 0) atomicAdd(&acc[img * 3 + 0], (double)v);
    v = blockReduce(syA, sw); if (tid == 0) atomicAdd(&acc[img * 3 + 1], (double)v);
    v = blockReduce(sxA, sw); if (tid == 0) atomicAdd(&acc[img * 3 + 2], (double)v);
}

// ---------------------------------------------------------------- final scalar
__global__ __launch_bounds__(256) void final_kernel(
        const double* __restrict__ acc, const double* __restrict__ pb,
        float* __restrict__ out) {
    const int tid = threadIdx.x;
    double si = 0.0, sp = 0.0, sy = 0.0;
    for (int i = tid; i < 1024; i += 256) {
        si += pb[i * 3 + 0]; sp += pb[i * 3 + 1]; sy += pb[i * 3 + 2];
    }
    #pragma unroll
    for (int o = 32; o; o >>= 1) {
        si += __shfl_down(si, o, 64);
        sp += __shfl_down(sp, o, 64);
        sy += __shfl_down(sy, o, 64);
    }
    __shared__ double dsw[3][4];
    int lane = tid & 63, wid = tid >> 6;
    if (lane == 0) { dsw[0][wid] = si; dsw[1][wid] = sp; dsw[2][wid] = sy; }
    __syncthreads();
    if (tid == 0) {
        double inter = dsw[0][0] + dsw[0][1] + dsw[0][2] + dsw[0][3];
        double sump  = dsw[1][0] + dsw[1][1] + dsw[1][2] + dsw[1][3];
        double sumy  = dsw[2][0] + dsw[2][1] + dsw[2][2] + dsw[2][3];
        double dsum = 0.0, csum = 0.0;
        for (int b = 0; b < B; ++b) {
            double tp = acc[b * 3 + 0], typ = acc[b * 3 + 1], txp = acc[b * 3 + 2];
            double tt = acc[(B + b) * 3 + 0], tyt = acc[(B + b) * 3 + 1], txt = acc[(B + b) * 3 + 2];
            double ycp = typ / (tp + 1e-8), xcp = txp / (tp + 1e-8);
            double yct = tyt / (tt + 1e-8), xct = txt / (tt + 1e-8);
            double dy = ycp - yct, dx = xcp - xct;
            dsum += sqrt(dy * dy + dx * dx);
            csum += fabs(tp - tt) / (tp + tt + 1e-8);
        }
        double diag = sqrt((double)(H * H + W * W));
        double distance_loss = (dsum / B) / (diag + 1e-8);
        double count_penalty = csum / B;
        double dice = 1.0 - (2.0 * inter + 1.0) / (sumy + sump + 1.0);
        out[0] = (float)(0.85 * dice + 0.15 * (distance_loss + count_penalty));
    }
}

// ---------------------------------------------------------------- launch
extern "C" void kernel_launch(void* const* d_in, const int* in_sizes, int n_in,
                              void* d_out, int out_size, void* d_ws, size_t ws_size,
                              hipStream_t stream) {
    const float* net = (const float*)d_in[0];   // [8,2,512,512] f32
    const int*   yt  = (const int*)d_in[1];     // [8,1,512,512] i32
    float* out = (float*)d_out;

    float* J0   = (float*)d_ws;                       // 16 MB
    float* J1   = J0 + (size_t)NIMG * S;              // 16 MB
    float* skel = J1 + (size_t)NIMG * S;              // 16 MB
    double* acc = (double*)(skel + (size_t)NIMG * S); // 48 doubles
    double* pb  = acc + 48;                           // 1024*3 doubles

    phase1_kernel<<<1024, 256, 0, stream>>>(net, yt, J0, pb, acc);

    // 41 rounds = 6 dispatches x 6 + 1 dispatch x 5
    skel_fused_kernel<true><<<NIMG * 64, 512, 0, stream>>>(J0, J1, skel, 6);
    float* a = J1; float* b = J0;
    for (int p = 1; p < 7; ++p) {
        int nr = (p == 6) ? 5 : 6;
        skel_fused_kernel<false><<<NIMG * 64, 512, 0, stream>>>(a, b, skel, nr);
        float* tmp = a; a = b; b = tmp;
    }

    endpoint_kernel<<<NIMG * 64, 256, 0, stream>>>(skel, acc);
    final_kernel<<<1, 256, 0, stream>>>(acc, pb, out);
}

// Round 10
// 338.259 us; speedup vs baseline: 1.1293x; 1.1293x over previous
//
#include <hip/hip_runtime.h>
#include <math.h>

#define W 512
#define H 512
#define S (W * H)        // 262144
#define B 8
#define NIMG 16
#define CORE 64
#define LDT 88           // tile cols
#define LROWS 90         // LDS rows 0..89 all loaded; image(r) = yb + r
#define NQ 22            // quads per row
#define FINF __builtin_huge_valf()

__device__ __forceinline__ float4 ld4s(const float* p) { return *(const float4*)p; }
__device__ __forceinline__ void st4s(float* p, float4 v) { *(float4*)p = v; }

__device__ __forceinline__ float blockReduce(float v, float* sw) {
    #pragma unroll
    for (int o = 32; o; o >>= 1) v += __shfl_down(v, o, 64);
    int lane = threadIdx.x & 63, wid = threadIdx.x >> 6;
    if (lane == 0) sw[wid] = v;
    __syncthreads();
    float r = (threadIdx.x < 4) ? sw[threadIdx.x] : 0.f;
    if (wid == 0) { r += __shfl_down(r, 2, 64); r += __shfl_down(r, 1, 64); }
    __syncthreads();
    return r;
}

// ---------------------------------------------------------------- phase 1
__global__ __launch_bounds__(256) void phase1_kernel(
        const float* __restrict__ net, const int* __restrict__ yt,
        float* __restrict__ J0, double* __restrict__ pb,
        double* __restrict__ acc) {
    __shared__ float sw[4];
    const int tid = threadIdx.x;
    if (blockIdx.x == 0 && tid < 48) acc[tid] = 0.0;
    float inter = 0.f, sp = 0.f, sy = 0.f;
    for (int i = blockIdx.x * 256 + tid; i < B * S / 4; i += 1024 * 256) {
        int b = i >> 16;
        int s = (i & 65535) << 2;
        const float* nb = net + (size_t)b * 2 * S;
        float4 x0 = ld4s(nb + s);
        float4 x1 = ld4s(nb + S + s);
        int4 yv = *(const int4*)(yt + (size_t)b * S + s);
        float4 p, yf;
        p.x = 1.f / (1.f + expf(x0.x - x1.x));
        p.y = 1.f / (1.f + expf(x0.y - x1.y));
        p.z = 1.f / (1.f + expf(x0.z - x1.z));
        p.w = 1.f / (1.f + expf(x0.w - x1.w));
        yf.x = (float)yv.x; yf.y = (float)yv.y; yf.z = (float)yv.z; yf.w = (float)yv.w;
        st4s(J0 + (size_t)b * S + s, p);
        st4s(J0 + (size_t)(B + b) * S + s, yf);
        inter += p.x * yf.x + p.y * yf.y + p.z * yf.z + p.w * yf.w;
        sp += p.x + p.y + p.z + p.w;
        sy += yf.x + yf.y + yf.z + yf.w;
    }
    float v;
    v = blockReduce(inter, sw); if (tid == 0) pb[blockIdx.x * 3 + 0] = (double)v;
    v = blockReduce(sp, sw);    if (tid == 0) pb[blockIdx.x * 3 + 1] = (double)v;
    v = blockReduce(sy, sw);    if (tid == 0) pb[blockIdx.x * 3 + 2] = (double)v;
}

// ---------------------------------------------------------------- fused skeleton
// "r5-refined": in-place single 90x88 buffer (31.7 KB), 256 threads/4 waves,
// 5 blocks/CU capacity -> ALL 1024 blocks co-resident (zero tail).
// 2 barriers/round (r5's 3rd proven redundant: round r dilate-reads and round
// r+1 writes are separated by round r+1's post-read barrier).
// Fixed erode region rows 1..88 x quads 0..21: stale rows 0/89 + col sentinels
// creep <=1/round -> <=6 after 6 rounds; dilate touches rows 12..77, cols
// 11..76 -> margin >=7. Clamped-unit trick keeps shuffles wave-uniform.
template <bool INIT>
__global__ __launch_bounds__(256, 4) void skel_fused_kernel(
        const float* __restrict__ Jin, float* __restrict__ Jout,
        float* __restrict__ skel, int NR) {
    __shared__ float Jl[LROWS * LDT];   // 90 x 88 floats = 31680 B
    const int tid = threadIdx.x;
    const int lane = tid & 63;
    const int img = blockIdx.x >> 6;
    const int t64 = blockIdx.x & 63;
    const int ty = t64 >> 3, tx = t64 & 7;
    const int yb = ty * CORE - 13;      // image row of LDS row 0
    const int x0 = tx * CORE - 12;      // image col of LDS col 0
    const float* Ji = Jin + (size_t)img * S;
    float* Jo = Jout + (size_t)img * S;
    float* Sk = skel + (size_t)img * S;
    const bool interior = (ty > 0) & (ty < 7) & (tx > 0) & (tx < 7);

    // ---- load 90x88 tile (rows 0..89; quads all-in/out in x)
    if (interior) {
        for (int i = tid; i < LROWS * NQ; i += 256) {
            int r = i / NQ, q = i - (i / NQ) * NQ;
            st4s(&Jl[r * LDT + (q << 2)],
                 ld4s(Ji + (yb + r) * W + x0 + (q << 2)));
        }
    } else {
        for (int i = tid; i < LROWS * NQ; i += 256) {
            int r = i / NQ, q = i - (i / NQ) * NQ;
            int gy = yb + r, gx = x0 + (q << 2);
            float4 v;
            if ((unsigned)gy < H && (unsigned)gx < W) v = ld4s(Ji + gy * W + gx);
            else v = make_float4(FINF, FINF, FINF, FINF);
            st4s(&Jl[r * LDT + (q << 2)], v);
        }
    }

    // ---- dilate ownership: thread = (sq, ss): core quad col sq, rows 4ss..4ss+3
    const int sq = tid & 15, ss = tid >> 4;     // sq 0..15, ss 0..15
    const int tcol = 12 + (sq << 2);            // tile col of core quad
    const int gxc = tx * CORE + (sq << 2);      // global col of core quad
    const int trow = 13 + (ss << 2);            // tile row of slab start
    const int grow = ty * CORE + (ss << 2);     // global row of slab start
    float4 sk4[4];
    #pragma unroll
    for (int j = 0; j < 4; ++j) {
        if (INIT) sk4[j] = make_float4(0.f, 0.f, 0.f, 0.f);
        else      sk4[j] = ld4s(Sk + (grow + j) * W + gxc);
    }
    __syncthreads();   // tile loaded

    // carried old-J core rows (tile rows trow..trow+3) — read before round 0 writes
    float4 Jc[4];
    #pragma unroll
    for (int j = 0; j < 4; ++j) Jc[j] = ld4s(Jl + (trow + j) * LDT + tcol);

    for (int rr = 0; rr < NR; ++rr) {
        // ---------------- READ PHASE: erode into registers (2 sweeps) ----------------
        float4 Er[2][4];
        int rb2[2], cc2[2];
        bool act2[2];
        #pragma unroll
        for (int s2 = 0; s2 < 2; ++s2) {
            const int uraw = tid + (s2 << 8);
            act2[s2] = (uraw < 484);
            const int u = (uraw < 484) ? uraw : 483;   // clamp: uniform shuffles
            const int ei = u / 22;
            const int eq = u - ei * 22;
            const int rb = 1 + (ei << 2);
            const int cc = eq << 2;
            rb2[s2] = rb; cc2[s2] = cc;
            const float* bp = Jl + (rb - 1) * LDT + cc;
            float4 wA = ld4s(bp);           // row rb-1
            float4 wB = ld4s(bp + LDT);     // row rb
            const bool cOOB = (!interior) && ((unsigned)(x0 + cc) >= W);
            #pragma unroll
            for (int j = 0; j < 4; ++j) {
                float4 wC = ld4s(bp + (j + 2) * LDT);   // row rb+j+1
                float lw = __shfl_up(wB.w, 1, 64);
                float rx = __shfl_down(wB.x, 1, 64);
                if (lane == 0 && eq > 0)   lw = Jl[(rb + j) * LDT + cc - 1];
                if (lane == 63 && eq < 21) rx = Jl[(rb + j) * LDT + cc + 4];
                if (eq == 0)  lw = FINF;    // tile edge sentinel (creep-safe)
                if (eq == 21) rx = FINF;
                float4 e;
                e.x = fminf(fminf(fminf(wA.x, wC.x), fminf(lw,   wB.y)), wB.x);
                e.y = fminf(fminf(fminf(wA.y, wC.y), fminf(wB.x, wB.z)), wB.y);
                e.z = fminf(fminf(fminf(wA.z, wC.z), fminf(wB.y, wB.w)), wB.z);
                e.w = fminf(fminf(fminf(wA.w, wC.w), fminf(wB.z, rx  )), wB.w);
                if (!interior) {
                    int gy = yb + rb + j;
                    if (((unsigned)gy >= H) | cOOB)
                        e = make_float4(FINF, FINF, FINF, FINF);   // minpool pad
                }
                Er[s2][j] = e;
                wA = wB; wB = wC;
            }
        }
        __syncthreads();   // B1: all reads of old J complete

        // ---------------- WRITE PHASE (in place) ----------------
        #pragma unroll
        for (int s2 = 0; s2 < 2; ++s2) {
            if (act2[s2]) {
                #pragma unroll
                for (int j = 0; j < 4; ++j)
                    st4s(&Jl[(rb2[s2] + j) * LDT + cc2[s2]], Er[s2][j]);
            }
        }
        __syncthreads();   // B2: E visible to all

        // ------- DILATE (3x3 max) + delta + skel, 4-row slab per thread -------
        {
            const float* ebase = Jl + (trow - 1) * LDT + tcol;
            float4 E[6];
            #pragma unroll
            for (int j = 0; j < 6; ++j) E[j] = ld4s(ebase + j * LDT);
            float lwv[6], rxv[6];
            #pragma unroll
            for (int j = 0; j < 6; ++j) {
                lwv[j] = __shfl_up(E[j].w, 1, 64);
                rxv[j] = __shfl_down(E[j].x, 1, 64);
                if (sq == 0)  lwv[j] = (tx == 0) ? -FINF : Jl[(trow - 1 + j) * LDT + 11];
                if (sq == 15) rxv[j] = (tx == 7) ? -FINF : Jl[(trow - 1 + j) * LDT + 76];
            }
            float4 hx[6];
            #pragma unroll
            for (int j = 0; j < 6; ++j) {
                hx[j].x = fmaxf(fmaxf(lwv[j], E[j].x), E[j].y);
                hx[j].y = fmaxf(fmaxf(E[j].x, E[j].y), E[j].z);
                hx[j].z = fmaxf(fmaxf(E[j].y, E[j].z), E[j].w);
                hx[j].w = fmaxf(fmaxf(E[j].z, E[j].w), rxv[j]);
            }
            #pragma unroll
            for (int j = 0; j < 4; ++j) {
                int gy = grow + j;
                float4 hm = hx[j], hp = hx[j + 2];
                if (!interior) {
                    if (gy == 0)     hm = make_float4(-FINF, -FINF, -FINF, -FINF);
                    if (gy == H - 1) hp = make_float4(-FINF, -FINF, -FINF, -FINF);
                }
                float4 dm;
                dm.x = fmaxf(fmaxf(hm.x, hx[j + 1].x), hp.x);
                dm.y = fmaxf(fmaxf(hm.y, hx[j + 1].y), hp.y);
                dm.z = fmaxf(fmaxf(hm.z, hx[j + 1].z), hp.z);
                dm.w = fmaxf(fmaxf(hm.w, hx[j + 1].w), hp.w);
                float4 Jv = Jc[j];
                float d0 = fmaxf(Jv.x - dm.x, 0.f);
                float d1 = fmaxf(Jv.y - dm.y, 0.f);
                float d2 = fmaxf(Jv.z - dm.z, 0.f);
                float d3 = fmaxf(Jv.w - dm.w, 0.f);
                sk4[j].x += fmaxf(d0 - sk4[j].x * d0, 0.f);
                sk4[j].y += fmaxf(d1 - sk4[j].y * d1, 0.f);
                sk4[j].z += fmaxf(d2 - sk4[j].z * d2, 0.f);
                sk4[j].w += fmaxf(d3 - sk4[j].w * d3, 0.f);
                Jc[j] = E[j + 1];   // new J core row -> next round / epilogue
            }
        }
        // no 3rd barrier: next round's B1 orders dilate-reads vs next writes
    }

    // epilogue: Jout = E_{NR-1} core (held in Jc), skel out
    #pragma unroll
    for (int j = 0; j < 4; ++j) {
        int gy = grow + j;
        st4s(Jo + gy * W + gxc, Jc[j]);
        st4s(Sk + gy * W + gxc, sk4[j]);
    }
}

// ---------------------------------------------------------------- endpoints
__global__ __launch_bounds__(256) void endpoint_kernel(
        const float* __restrict__ skel, double* __restrict__ acc) {
    __shared__ float sR[10][520];
    __shared__ float sw[4];
    const int tid = threadIdx.x;
    const int img = blockIdx.x >> 6;
    const int rb = blockIdx.x & 63;
    const int yB = rb << 3;
    const float* Sk = skel + (size_t)img * S;
    for (int i = tid; i < 1280; i += 256) {
        int r = i >> 7, c4 = i & 127;
        int gy = yB - 1 + r;
        float4 v = make_float4(0.f, 0.f, 0.f, 0.f);
        if ((unsigned)gy < H) v = ld4s(Sk + gy * W + (c4 << 2));
        st4s(&sR[r][4 + (c4 << 2)], v);
    }
    if (tid < 10) { sR[tid][3] = 0.f; sR[tid][516] = 0.f; }
    __syncthreads();
    float t = 0.f, syA = 0.f, sxA = 0.f;
    #pragma unroll
    for (int k = 0; k < 4; ++k) {
        int qidx = k * 256 + tid;
        int rrow = qidx >> 7;
        int x = (qidx & 127) << 2;
        int r = 1 + rrow;
        float gy = (float)(yB + rrow);
        const float* Rm = &sR[r - 1][4 + x];
        const float* Rc = &sR[r][4 + x];
        const float* Rp = &sR[r + 1][4 + x];
        float4 bm = ld4s(Rm); float lm = ld4s(Rm - 4).w, rm = ld4s(Rm + 4).x;
        float4 bc = ld4s(Rc); float lc = ld4s(Rc - 4).w, rc = ld4s(Rc + 4).x;
        float4 bp = ld4s(Rp); float lp = ld4s(Rp - 4).w, rp = ld4s(Rp + 4).x;
        float hm0 = lm + bm.x + bm.y, hm1 = bm.x + bm.y + bm.z;
        float hm2 = bm.y + bm.z + bm.w, hm3 = bm.z + bm.w + rm;
        float hc0 = lc + bc.x + bc.y, hc1 = bc.x + bc.y + bc.z;
        float hc2 = bc.y + bc.z + bc.w, hc3 = bc.z + bc.w + rc;
        float hp0 = lp + bp.x + bp.y, hp1 = bp.x + bp.y + bp.z;
        float hp2 = bp.y + bp.z + bp.w, hp3 = bp.z + bp.w + rp;
        float ns0 = hm0 + hc0 + hp0 + 9.f * bc.x;
        float ns1 = hm1 + hc1 + hp1 + 9.f * bc.y;
        float ns2 = hm2 + hc2 + hp2 + 9.f * bc.z;
        float ns3 = hm3 + hc3 + hp3 + 9.f * bc.w;
        float e0 = ns0 - 11.f, e1 = ns1 - 11.f, e2 = ns2 - 11.f, e3 = ns3 - 11.f;
        float ep0 = expf(-e0 * e0) * bc.x;
        float ep1 = expf(-e1 * e1) * bc.y;
        float ep2 = expf(-e2 * e2) * bc.z;
        float ep3 = expf(-e3 * e3) * bc.w;
        float es = ep0 + ep1 + ep2 + ep3;
        t += es;
        syA += gy * es;
        sxA += ep0 * (float)(x + 0) + ep1 * (float)(x + 1)
             + ep2 * (float)(x + 2) + ep3 * (float)(x + 3);
    }
    float v;
    v = blockReduce(t, sw);   if (tid == 0) atomicAdd(&acc[img * 3 + 0], (double)v);
    v = blockReduce(syA, sw); if (tid == 0) atomicAdd(&acc[img * 3 + 1], (double)v);
    v = blockReduce(sxA, sw); if (tid == 0) atomicAdd(&acc[img * 3 + 2], (double)v);
}

// ---------------------------------------------------------------- final scalar
__global__ __launch_bounds__(256) void final_kernel(
        const double* __restrict__ acc, const double* __restrict__ pb,
        float* __restrict__ out) {
    const int tid = threadIdx.x;
    double si = 0.0, sp = 0.0, sy = 0.0;
    for (int i = tid; i < 1024; i += 256) {
        si += pb[i * 3 + 0]; sp += pb[i * 3 + 1]; sy += pb[i * 3 + 2];
    }
    #pragma unroll
    for (int o = 32; o; o >>= 1) {
        si += __shfl_down(si, o, 64);
        sp += __shfl_down(sp, o, 64);
        sy += __shfl_down(sy, o, 64);
    }
    __shared__ double dsw[3][4];
    int lane = tid & 63, wid = tid >> 6;
    if (lane == 0) { dsw[0][wid] = si; dsw[1][wid] = sp; dsw[2][wid] = sy; }
    __syncthreads();
    if (tid == 0) {
        double inter = dsw[0][0] + dsw[0][1] + dsw[0][2] + dsw[0][3];
        double sump  = dsw[1][0] + dsw[1][1] + dsw[1][2] + dsw[1][3];
        double sumy  = dsw[2][0] + dsw[2][1] + dsw[2][2] + dsw[2][3];
        double dsum = 0.0, csum = 0.0;
        for (int b = 0; b < B; ++b) {
            double tp = acc[b * 3 + 0], typ = acc[b * 3 + 1], txp = acc[b * 3 + 2];
            double tt = acc[(B + b) * 3 + 0], tyt = acc[(B + b) * 3 + 1], txt = acc[(B + b) * 3 + 2];
            double ycp = typ / (tp + 1e-8), xcp = txp / (tp + 1e-8);
            double yct = tyt / (tt + 1e-8), xct = txt / (tt + 1e-8);
            double dy = ycp - yct, dx = xcp - xct;
            dsum += sqrt(dy * dy + dx * dx);
            csum += fabs(tp - tt) / (tp + tt + 1e-8);
        }
        double diag = sqrt((double)(H * H + W * W));
        double distance_loss = (dsum / B) / (diag + 1e-8);
        double count_penalty = csum / B;
        double dice = 1.0 - (2.0 * inter + 1.0) / (sumy + sump + 1.0);
        out[0] = (float)(0.85 * dice + 0.15 * (distance_loss + count_penalty));
    }
}

// ---------------------------------------------------------------- launch
extern "C" void kernel_launch(void* const* d_in, const int* in_sizes, int n_in,
                              void* d_out, int out_size, void* d_ws, size_t ws_size,
                              hipStream_t stream) {
    const float* net = (const float*)d_in[0];   // [8,2,512,512] f32
    const int*   yt  = (const int*)d_in[1];     // [8,1,512,512] i32
    float* out = (float*)d_out;

    float* J0   = (float*)d_ws;                       // 16 MB
    float* J1   = J0 + (size_t)NIMG * S;              // 16 MB
    float* skel = J1 + (size_t)NIMG * S;              // 16 MB
    double* acc = (double*)(skel + (size_t)NIMG * S); // 48 doubles
    double* pb  = acc + 48;                           // 1024*3 doubles

    phase1_kernel<<<1024, 256, 0, stream>>>(net, yt, J0, pb, acc);

    // 41 rounds = 6 dispatches x 6 + 1 dispatch x 5
    skel_fused_kernel<true><<<NIMG * 64, 256, 0, stream>>>(J0, J1, skel, 6);
    float* a = J1; float* b = J0;
    for (int p = 1; p < 7; ++p) {
        int nr = (p == 6) ? 5 : 6;
        skel_fused_kernel<false><<<NIMG * 64, 256, 0, stream>>>(a, b, skel, nr);
        float* tmp = a; a = b; b = tmp;
    }

    endpoint_kernel<<<NIMG * 64, 256, 0, stream>>>(skel, acc);
    final_kernel<<<1, 256, 0, stream>>>(acc, pb, out);
}